// Round 1
// baseline (563.456 us; speedup 1.0000x reference)
//
#include <hip/hip_runtime.h>
#include <hip/hip_bf16.h>

#define DIM 2048
#define NHEADS 16
#define HEAD_DIM 128
#define HIDDEN 2048
#define SEQ 4096
#define BATCH 2
#define BT (BATCH * SEQ)        // 8192
#define NSEG 64
#define SEGLEN (SEQ / NSEG)     // 64
#define N_GATE (3 * HIDDEN)     // 6144

typedef __bf16 bf16_t;
typedef __bf16 bf16x8 __attribute__((ext_vector_type(8)));
typedef __bf16 bf16x4_t __attribute__((ext_vector_type(4)));
typedef float f32x4 __attribute__((ext_vector_type(4)));

__device__ __forceinline__ void gload_lds16(const void* g, void* l) {
  __builtin_amdgcn_global_load_lds(
      (const __attribute__((address_space(1))) void*)g,
      (__attribute__((address_space(3))) void*)l, 16, 0, 0);
}

// ---------------- prep: f32 -> bf16 convert (vectorized) ----------------
__global__ void cvt_f32_bf16(const float* __restrict__ src, bf16_t* __restrict__ dst, int n4) {
  int i = blockIdx.x * blockDim.x + threadIdx.x;
  if (i >= n4) return;
  float4 v = reinterpret_cast<const float4*>(src)[i];
  bf16x4_t o;
  o[0] = (bf16_t)v.x; o[1] = (bf16_t)v.y; o[2] = (bf16_t)v.z; o[3] = (bf16_t)v.w;
  reinterpret_cast<bf16x4_t*>(dst)[i] = o;
}

// ---------------- f gate in pure fp32 (precision-critical) ----------------
// one thread per (bt, head); 16 lanes of a wave share the x row (broadcast loads)
__global__ void fgate_kernel(const float* __restrict__ x, const float* __restrict__ Wg,
                             const float* __restrict__ bg, float* __restrict__ fout) {
  int idx = blockIdx.x * 256 + threadIdx.x;
  int bt = idx >> 4, h = idx & 15;
  const float* xr = x + (size_t)bt * DIM;
  const float* wr = Wg + (size_t)h * DIM;
  float acc = 0.f;
  for (int k = 0; k < DIM; k += 4) {
    float4 xv = *reinterpret_cast<const float4*>(xr + k);
    float4 wv = *reinterpret_cast<const float4*>(wr + k);
    acc = fmaf(xv.x, wv.x, acc);
    acc = fmaf(xv.y, wv.y, acc);
    acc = fmaf(xv.z, wv.z, acc);
    acc = fmaf(xv.w, wv.w, acc);
  }
  acc += bg[h];
  fout[idx] = 1.f / (1.f + expf(-acc));
}

// ---------------- m97-structure 128x128 bf16 MFMA GEMM, A(MxK) * B(NxK)^T ----------------
// MODE 0: gates GEMM. cols [0,2048)->sigmoid->Oi, [2048,4096)->tanh->Ot, [4096,6144)->Oo
// MODE 1: output GEMM. add bias, store fp32 to Of
template <int MODE>
__global__ void gemm_bt(const bf16_t* __restrict__ A, const bf16_t* __restrict__ B,
                        const float* __restrict__ bias,
                        bf16_t* __restrict__ Oi, bf16_t* __restrict__ Ot,
                        bf16_t* __restrict__ Oo, float* __restrict__ Of,
                        int K) {
  __shared__ __align__(16) bf16_t As[128 * 32];
  __shared__ __align__(16) bf16_t Bs[128 * 32];
  const int tid = threadIdx.x;
  const int wave = tid >> 6, lane = tid & 63;
  const int brow = blockIdx.y * 128, bcol = blockIdx.x * 128;
  const int wm = wave >> 1, wn = wave & 1;

  f32x4 acc[4][4] = {};

  const int ldrow = lane >> 2;            // 0..15 within a 16-row group
  const int ldcol = (lane & 3) * 8;       // bf16 elements (16B chunks)

  for (int k0 = 0; k0 < K; k0 += 32) {
#pragma unroll
    for (int j = 0; j < 2; ++j) {
      int rg = wave * 2 + j;              // 16-row group 0..7
      int row = rg * 16 + ldrow;
      gload_lds16(A + (size_t)(brow + row) * K + k0 + ldcol, &As[rg * 16 * 32]);
      gload_lds16(B + (size_t)(bcol + row) * K + k0 + ldcol, &Bs[rg * 16 * 32]);
    }
    __syncthreads();

    bf16x8 af[4], bfr[4];
#pragma unroll
    for (int mi = 0; mi < 4; ++mi)
      af[mi] = *reinterpret_cast<const bf16x8*>(
          &As[(wm * 64 + mi * 16 + (lane & 15)) * 32 + (lane >> 4) * 8]);
#pragma unroll
    for (int ni = 0; ni < 4; ++ni)
      bfr[ni] = *reinterpret_cast<const bf16x8*>(
          &Bs[(wn * 64 + ni * 16 + (lane & 15)) * 32 + (lane >> 4) * 8]);
#pragma unroll
    for (int mi = 0; mi < 4; ++mi)
#pragma unroll
      for (int ni = 0; ni < 4; ++ni)
        acc[mi][ni] = __builtin_amdgcn_mfma_f32_16x16x32_bf16(af[mi], bfr[ni], acc[mi][ni], 0, 0, 0);
    __syncthreads();
  }

  // epilogue. C/D layout: col = lane&15, row = (lane>>4)*4 + q  [verified m89/m91]
  const int crow0 = brow + wm * 64;
  const int ccol0 = bcol + wn * 64;
  if (MODE == 0) {
    const int section = bcol >> 11;  // tile lies fully inside one 2048-section
    bf16_t* dst = (section == 0) ? Oi : ((section == 1) ? Ot : Oo);
#pragma unroll
    for (int mi = 0; mi < 4; ++mi)
#pragma unroll
      for (int ni = 0; ni < 4; ++ni) {
        int gcol = ccol0 + ni * 16 + (lane & 15);
        int col = gcol & 2047;
        float b = bias[gcol];
#pragma unroll
        for (int q = 0; q < 4; ++q) {
          int row = crow0 + mi * 16 + (lane >> 4) * 4 + q;
          float v = acc[mi][ni][q] + b;
          float a;
          if (section == 0)      a = 1.f / (1.f + __expf(-v));
          else if (section == 1) a = tanhf(v);
          else                   a = v;
          dst[(size_t)row * HIDDEN + col] = (bf16_t)a;
        }
      }
  } else {
#pragma unroll
    for (int mi = 0; mi < 4; ++mi)
#pragma unroll
      for (int ni = 0; ni < 4; ++ni) {
        int col = ccol0 + ni * 16 + (lane & 15);
        float b = bias[col];
#pragma unroll
        for (int q = 0; q < 4; ++q) {
          int row = crow0 + mi * 16 + (lane >> 4) * 4 + q;
          Of[(size_t)row * DIM + col] = acc[mi][ni][q] + b;
        }
      }
  }
}

// ---------------- segmented scan ----------------
// pass1: per (b, seg, ch): local c_end (c init 0) and P = prod f over segment
__global__ void scan_pass1(const float* __restrict__ fg, const bf16_t* __restrict__ gi,
                           const bf16_t* __restrict__ gt, float* __restrict__ cend,
                           float* __restrict__ pseg) {
  int bx = blockIdx.x;
  int chblk = bx & 7, seg = (bx >> 3) & 63, b = bx >> 9;
  int ch = chblk * 256 + threadIdx.x;
  int head = ch >> 7;
  float c = 0.f, P = 1.f;
  size_t t0 = (size_t)b * SEQ + (size_t)seg * SEGLEN;
  for (int tt = 0; tt < SEGLEN; ++tt) {
    size_t bt = t0 + tt;
    float f = fg[bt * NHEADS + head];
    float iv = (float)gi[bt * HIDDEN + ch];
    float tv = (float)gt[bt * HIDDEN + ch];
    c = fmaf(f, c, iv * tv);
    P *= f;
  }
  size_t o = ((size_t)b * NSEG + seg) * HIDDEN + ch;
  cend[o] = c;
  pseg[o] = P;
}

// pass2: sequential combine over the 64 segments (tiny)
__global__ void scan_pass2(const float* __restrict__ cend, const float* __restrict__ pseg,
                           float* __restrict__ cin) {
  int idx = blockIdx.x * 256 + threadIdx.x;  // 4096
  int b = idx >> 11, ch = idx & 2047;
  float C = 0.f;
  for (int s = 0; s < NSEG; ++s) {
    size_t o = ((size_t)b * NSEG + s) * HIDDEN + ch;
    cin[o] = C;
    C = cend[o] + pseg[o] * C;
  }
}

// pass3: replay with carry-in, compute h = o * tanh(c), store bf16
__global__ void scan_pass3(const float* __restrict__ fg, const bf16_t* __restrict__ gi,
                           const bf16_t* __restrict__ gt, const bf16_t* __restrict__ go,
                           const float* __restrict__ cin, bf16_t* __restrict__ h) {
  int bx = blockIdx.x;
  int chblk = bx & 7, seg = (bx >> 3) & 63, b = bx >> 9;
  int ch = chblk * 256 + threadIdx.x;
  int head = ch >> 7;
  float c = cin[((size_t)b * NSEG + seg) * HIDDEN + ch];
  size_t t0 = (size_t)b * SEQ + (size_t)seg * SEGLEN;
  for (int tt = 0; tt < SEGLEN; ++tt) {
    size_t bt = t0 + tt;
    float f = fg[bt * NHEADS + head];
    float iv = (float)gi[bt * HIDDEN + ch];
    float tv = (float)gt[bt * HIDDEN + ch];
    c = fmaf(f, c, iv * tv);
    float hv = (float)go[bt * HIDDEN + ch] * tanhf(c);
    h[bt * HIDDEN + ch] = (bf16_t)hv;
  }
}

extern "C" void kernel_launch(void* const* d_in, const int* in_sizes, int n_in,
                              void* d_out, int out_size, void* d_ws, size_t ws_size,
                              hipStream_t stream) {
  const float* x  = (const float*)d_in[0];
  const float* Wg = (const float*)d_in[1];
  const float* bg = (const float*)d_in[2];
  const float* Wo = (const float*)d_in[3];
  const float* bo = (const float*)d_in[4];
  float* out = (float*)d_out;

  char* ws = (char*)d_ws;
  size_t off = 0;
  auto alloc = [&](size_t bytes) -> void* {
    void* p = ws + off;
    off += (bytes + 255) & ~(size_t)255;
    return p;
  };
  bf16_t* xb   = (bf16_t*)alloc((size_t)BT * DIM * 2);
  bf16_t* wgb  = (bf16_t*)alloc((size_t)N_GATE * DIM * 2);
  bf16_t* wob  = (bf16_t*)alloc((size_t)DIM * HIDDEN * 2);
  float*  fg   = (float*)alloc((size_t)BT * NHEADS * 4);
  bf16_t* gi   = (bf16_t*)alloc((size_t)BT * HIDDEN * 2);
  bf16_t* gt   = (bf16_t*)alloc((size_t)BT * HIDDEN * 2);
  bf16_t* go   = (bf16_t*)alloc((size_t)BT * HIDDEN * 2);
  bf16_t* hbuf = (bf16_t*)alloc((size_t)BT * HIDDEN * 2);
  float*  cend = (float*)alloc((size_t)BATCH * NSEG * HIDDEN * 4);
  float*  pseg = (float*)alloc((size_t)BATCH * NSEG * HIDDEN * 4);
  float*  cin  = (float*)alloc((size_t)BATCH * NSEG * HIDDEN * 4);
  (void)ws_size; (void)in_sizes; (void)n_in; (void)out_size;

  // prep converts
  {
    int n4 = BT * DIM / 4;
    cvt_f32_bf16<<<(n4 + 255) / 256, 256, 0, stream>>>(x, xb, n4);
  }
  {
    int n4 = N_GATE * DIM / 4;
    cvt_f32_bf16<<<(n4 + 255) / 256, 256, 0, stream>>>(Wg + (size_t)NHEADS * DIM, wgb, n4);
  }
  {
    int n4 = DIM * HIDDEN / 4;
    cvt_f32_bf16<<<(n4 + 255) / 256, 256, 0, stream>>>(Wo, wob, n4);
  }

  // f gate in fp32
  fgate_kernel<<<(BT * NHEADS) / 256, 256, 0, stream>>>(x, Wg, bg, fg);

  // gates GEMM: M=8192, N=6144, K=2048
  gemm_bt<0><<<dim3(N_GATE / 128, BT / 128), 256, 0, stream>>>(
      xb, wgb, bg + NHEADS, gi, gt, go, nullptr, DIM);

  // segmented scan
  scan_pass1<<<BATCH * NSEG * (HIDDEN / 256), 256, 0, stream>>>(fg, gi, gt, cend, pseg);
  scan_pass2<<<BATCH * HIDDEN / 256, 256, 0, stream>>>(cend, pseg, cin);
  scan_pass3<<<BATCH * NSEG * (HIDDEN / 256), 256, 0, stream>>>(fg, gi, gt, go, cin, hbuf);

  // output GEMM: M=8192, N=2048, K=2048
  gemm_bt<1><<<dim3(DIM / 128, BT / 128), 256, 0, stream>>>(
      hbuf, wob, bo, nullptr, nullptr, nullptr, out, HIDDEN);
}